// Round 8
// baseline (412.361 us; speedup 1.0000x reference)
//
#include <hip/hip_runtime.h>
#include <cstdint>
#include <cstddef>

#define D_MODEL 1024
#define D_INNER 2048
#define D_STATE 16
#define SEQ     2048
#define NROWS   4096   // B * SEQ

typedef short short4v __attribute__((ext_vector_type(4)));
typedef short short8v __attribute__((ext_vector_type(8)));
typedef float float4v __attribute__((ext_vector_type(4)));

__device__ __forceinline__ float bf2f(short u) {
  union { unsigned int i; float f; } v;
  v.i = ((unsigned int)(unsigned short)u) << 16;
  return v.f;
}
__device__ __forceinline__ short f2bf(float f) {
  union { float f; unsigned int i; } v; v.f = f;
  unsigned int r = v.i + 0x7FFFu + ((v.i >> 16) & 1u);  // RNE
  return (short)(r >> 16);
}
// dtype-flagged scalar load: f32==1 -> float*, else bf16
__device__ __forceinline__ float lde(const void* p, size_t i, int f32) {
  return f32 ? ((const float*)p)[i] : bf2f(((const short*)p)[i]);
}
__device__ __forceinline__ void async16(short* lds, const short* g) {
  __builtin_amdgcn_global_load_lds(
      (const __attribute__((address_space(1))) unsigned int*)g,
      (__attribute__((address_space(3))) unsigned int*)lds, 16, 0, 0);
}

// -------- dtype probe ----------
__global__ __launch_bounds__(64) void probe_kernel(const unsigned int* __restrict__ xw,
                                                   int* __restrict__ flag) {
  int cnt = 0;
  for (int i = threadIdx.x; i < 1024; i += 64) {
    unsigned e = (xw[i] >> 7) & 0xFFu;
    cnt += (e >= 100u && e <= 150u) ? 1 : 0;
  }
  #pragma unroll
  for (int o = 32; o >= 1; o >>= 1) cnt += __shfl_xor(cnt, o);
  if (threadIdx.x == 0) *flag = (cnt < 614) ? 1 : 0;   // 1 => fp32 inputs
}

// -------- convert weights to bf16: [W_in | W_dt;W_B;W_C;pad | W_out] ----------
#define WIN_N  4194304u                 // 4096*1024
#define WDT_N  4194304u                 // 2048*2048
#define WBC_N  32768u                   // 16*2048
#define WPAD_N 196608u                  // 96*2048  (zero pad rows 2080..2175)
#define WCAT_N (WDT_N + 2u*WBC_N + WPAD_N)   // 2176*2048 = 4456448
#define WOUT_N 2097152u                 // 1024*2048
__global__ __launch_bounds__(256) void cvt_kernel(
    const void* __restrict__ Win, const void* __restrict__ Wdt,
    const void* __restrict__ WBp, const void* __restrict__ WCp,
    const void* __restrict__ Wout, short* __restrict__ dst,
    const int* __restrict__ flag) {
  const int f32 = *flag;
  const size_t i = ((size_t)blockIdx.x * 256 + threadIdx.x) * 8;
  const void* src = nullptr; size_t off = 0; bool zero = false;
  if (i < WIN_N) { src = Win; off = i; }
  else {
    size_t j = i - WIN_N;
    if (j < WDT_N) { src = Wdt; off = j; }
    else {
      j -= WDT_N;
      if (j < WBC_N) { src = WBp; off = j; }
      else {
        j -= WBC_N;
        if (j < WBC_N) { src = WCp; off = j; }
        else {
          j -= WBC_N;
          if (j < WPAD_N) zero = true;
          else { src = Wout; off = j - WPAD_N; }
        }
      }
    }
  }
  short8v o;
  if (zero) {
    #pragma unroll
    for (int j = 0; j < 8; ++j) o[j] = 0;
  } else if (f32) {
    const float* s = (const float*)src + off;
    #pragma unroll
    for (int j = 0; j < 8; ++j) o[j] = f2bf(s[j]);
  } else {
    o = *(const short8v*)((const short*)src + off);
  }
  *(short8v*)&dst[i] = o;
}

// -------- LayerNorm ----------
__global__ __launch_bounds__(256) void ln_kernel(
    const void* __restrict__ x, const void* __restrict__ w,
    const void* __restrict__ bb, short* __restrict__ xn,
    const int* __restrict__ flag) {
  const int f32 = *flag;
  const int row = blockIdx.x;
  const int tid = threadIdx.x;
  float v0, v1, v2, v3;
  if (f32) {
    float4v xv = ((const float4v*)((const float*)x + (size_t)row * D_MODEL))[tid];
    v0 = xv[0]; v1 = xv[1]; v2 = xv[2]; v3 = xv[3];
  } else {
    short4v xv = *(const short4v*)&((const short*)x)[(size_t)row * D_MODEL + tid * 4];
    v0 = bf2f(xv[0]); v1 = bf2f(xv[1]); v2 = bf2f(xv[2]); v3 = bf2f(xv[3]);
  }
  float s = v0 + v1 + v2 + v3;
  float q = v0*v0 + v1*v1 + v2*v2 + v3*v3;
  #pragma unroll
  for (int off = 32; off >= 1; off >>= 1) {
    s += __shfl_xor(s, off);
    q += __shfl_xor(q, off);
  }
  __shared__ float red[8];
  const int wid = tid >> 6;
  if ((tid & 63) == 0) { red[wid] = s; red[4 + wid] = q; }
  __syncthreads();
  s = red[0] + red[1] + red[2] + red[3];
  q = red[4] + red[5] + red[6] + red[7];
  const float mu = s * (1.f / 1024.f);
  const float var = q * (1.f / 1024.f) - mu * mu;
  const float rstd = rsqrtf(var + 1e-5f);
  short4v ov;
  #pragma unroll
  for (int j = 0; j < 4; ++j) {
    const float vj = (j == 0) ? v0 : (j == 1) ? v1 : (j == 2) ? v2 : v3;
    const float o = (vj - mu) * rstd * lde(w, tid * 4 + j, f32) + lde(bb, tid * 4 + j, f32);
    ov[j] = f2bf(o);
  }
  *(short4v*)&xn[(size_t)row * D_MODEL + tid * 4] = ov;
}

// -------- MFMA GEMM: C[m,n] = sum_k A[m,k]*B[n,k]; A row stride lda, B stride K
// Tile BM x 128. BM=256: 512 thr, double-buffer, vmcnt(3) distance-1 (R4 cfg).
// BM=128: 256 thr, QUAD-buffer ring, distance-3 vmcnt(12) steady state (R5 cfg
// -- the measured-best gemm1/gemm2 schedule: 85.2us on the dt GEMM).
// LDS chunk-XOR swizzle: slot chunk c of row r holds global chunk c^((r>>1)&3);
// applied on global SOURCE at stage time and on ds_read addr at use.
// MODE 0: bf16 store row-major (stride N)
// MODE 1: col<2048 -> softplus(acc+bias[col]) bf16 into Cv (stride 2048);
//         2048..2063 -> Bmo fp32 [row][16]; 2064..2079 -> Cmo; >=2080 discard
// MODE 2: acc+resid -> dtype-flagged store (stride N)
template <int MODE, int BM>
__global__ __launch_bounds__(2 * BM) void gemm_bt(
    const short* __restrict__ A, int lda, const short* __restrict__ B,
    void* __restrict__ Cv, int N, int K, const void* __restrict__ aux,
    float* __restrict__ Bmo, float* __restrict__ Cmo,
    const int* __restrict__ flag) {
  constexpr int NBUF = (BM == 256) ? 2 : 4;
  __shared__ __align__(16) short As[NBUF][BM * 32];
  __shared__ __align__(16) short Bs[NBUF][128 * 32];
  const int f32 = *flag;
  const int tid = threadIdx.x;
  const int bm = blockIdx.y * BM;
  const int bn = blockIdx.x << 7;
  const int wid = tid >> 6;
  const int lane = tid & 63;
  const int wm = (wid >> 1) << 6;
  const int wn = (wid & 1) << 6;

  float4v acc[4][4];
  #pragma unroll
  for (int i = 0; i < 4; ++i)
    #pragma unroll
    for (int j = 0; j < 4; ++j) acc[i][j] = (float4v){0.f, 0.f, 0.f, 0.f};

  const int srow = tid >> 2;            // 0 .. BM/2-1
  const int scol = (((tid & 3) ^ ((tid >> 3) & 3)) << 3);   // source chunk-XOR
  const short* ga = A + (size_t)(bm + srow) * lda + scol;
  const short* gb = B + (size_t)(bn + srow) * K + scol;   // srow < 128 needed for BM=256 single-DMA B
  const size_t astep = (size_t)(BM / 2) * lda;
  const size_t bstep = (size_t)64 * K;

  const int fr = lane & 15;
  const int fq = (((lane >> 4) ^ ((lane >> 1) & 3)) << 3);  // read chunk-XOR

#define STAGE(Ad, Bd, kk) do {                              \
    async16(&Ad[tid * 8], ga + (kk));                       \
    async16(&Ad[BM * 16 + tid * 8], ga + astep + (kk));     \
    if (BM == 256) {                                        \
      async16(&Bd[tid * 8], gb + (kk));                     \
    } else {                                                \
      async16(&Bd[tid * 8], gb + (kk));                     \
      async16(&Bd[2048 + tid * 8], gb + bstep + (kk));      \
    } } while (0)
#define VMW(NW) __builtin_amdgcn_s_waitcnt(0x3FF0 | (NW))
#define BAR __builtin_amdgcn_s_barrier()

  auto compute = [&](const short* Asrc, const short* Bsrc) {
    short8v af[4], bfv[4];
    #pragma unroll
    for (int i = 0; i < 4; ++i)
      af[i] = *(const short8v*)&Asrc[(wm + i * 16 + fr) * 32 + fq];
    #pragma unroll
    for (int j = 0; j < 4; ++j)
      bfv[j] = *(const short8v*)&Bsrc[(wn + j * 16 + fr) * 32 + fq];
    #pragma unroll
    for (int i = 0; i < 4; ++i)
      #pragma unroll
      for (int j = 0; j < 4; ++j)
        acc[i][j] = __builtin_amdgcn_mfma_f32_16x16x32_bf16(af[i], bfv[j], acc[i][j], 0, 0, 0);
  };

  const int nk = K >> 5;   // multiple of 4 for all our K
  if constexpr (BM == 128) {
    // quad-buffer ring, prefetch distance 3 (3 stages x 4 DMAs in flight)
    STAGE(As[0], Bs[0], 0);
    STAGE(As[1], Bs[1], 32);
    STAGE(As[2], Bs[2], 64);
    int c = 0;
    for (; c + 4 < nk; c += 4) {
      STAGE(As[3], Bs[3], (c + 3) << 5); VMW(12); BAR; compute(As[0], Bs[0]); BAR;
      STAGE(As[0], Bs[0], (c + 4) << 5); VMW(12); BAR; compute(As[1], Bs[1]); BAR;
      STAGE(As[1], Bs[1], (c + 5) << 5); VMW(12); BAR; compute(As[2], Bs[2]); BAR;
      STAGE(As[2], Bs[2], (c + 6) << 5); VMW(12); BAR; compute(As[3], Bs[3]); BAR;
    }
    // c == nk-4: drain 12 -> 8 -> 4 -> 0
    STAGE(As[3], Bs[3], (nk - 1) << 5); VMW(12); BAR; compute(As[0], Bs[0]); BAR;
    VMW(8); BAR; compute(As[1], Bs[1]); BAR;
    VMW(4); BAR; compute(As[2], Bs[2]); BAR;
    VMW(0); BAR; compute(As[3], Bs[3]);
  } else {
    STAGE(As[0], Bs[0], 0);
    for (int k2 = 0; k2 < nk; k2 += 2) {
      STAGE(As[1], Bs[1], (k2 + 1) << 5);
      VMW(3);
      BAR;
      compute(As[0], Bs[0]);
      BAR;
      if (k2 + 2 < nk) {
        STAGE(As[0], Bs[0], (k2 + 2) << 5);
        VMW(3);
      } else {
        VMW(0);
      }
      BAR;
      compute(As[1], Bs[1]);
      BAR;
    }
  }
#undef STAGE
#undef VMW
#undef BAR

  const int er = (lane >> 4) << 2;
  const int ec = lane & 15;
  #pragma unroll
  for (int i = 0; i < 4; ++i) {
    #pragma unroll
    for (int j = 0; j < 4; ++j) {
      const int gcol = bn + wn + j * 16 + ec;
      #pragma unroll
      for (int r = 0; r < 4; ++r) {
        const int grow = bm + wm + i * 16 + er + r;
        float v = acc[i][j][r];
        if (MODE == 1) {
          if (gcol < 2048) {
            v += lde(aux, gcol, f32);
            v = (v > 15.f) ? v : log1pf(__expf(v));
            ((short*)Cv)[(size_t)grow * 2048 + gcol] = f2bf(v);
          } else if (gcol < 2064) {
            Bmo[(size_t)grow * 16 + (gcol - 2048)] = v;
          } else if (gcol < 2080) {
            Cmo[(size_t)grow * 16 + (gcol - 2064)] = v;
          }
        } else {
          const size_t idx = (size_t)grow * N + gcol;
          if (MODE == 2) {
            v += lde(aux, idx, f32);
            if (f32) ((float*)Cv)[idx] = v;
            else     ((short*)Cv)[idx] = f2bf(v);
          } else {
            ((short*)Cv)[idx] = f2bf(v);
          }
        }
      }
    }
  }
}

// -------- causal depthwise conv (K=4) + SiLU, 8 rows/block, sliding window ----
#define CONV_RPB 8
__global__ __launch_bounds__(256) void conv_silu(
    const short* __restrict__ xz, const void* __restrict__ cw,
    const void* __restrict__ cb, short* __restrict__ xc,
    const int* __restrict__ flag) {
  const int f32 = *flag;
  const int r0 = blockIdx.x * CONV_RPB;
  const int c0 = threadIdx.x << 3;
  const int t0 = r0 & (SEQ - 1);     // 2048 % CONV_RPB == 0: no block straddles a batch boundary

  float wreg[32], bias[8];
  if (f32) {
    const float4v* wp = (const float4v*)((const float*)cw + (size_t)c0 * 4);
    #pragma unroll
    for (int q = 0; q < 8; ++q) {
      const float4v v = wp[q];
      #pragma unroll
      for (int k = 0; k < 4; ++k) wreg[q * 4 + k] = v[k];
    }
    const float4v* bp = (const float4v*)((const float*)cb + c0);
    const float4v b0 = bp[0], b1 = bp[1];
    #pragma unroll
    for (int j = 0; j < 4; ++j) { bias[j] = b0[j]; bias[4 + j] = b1[j]; }
  } else {
    const short8v* wp = (const short8v*)((const short*)cw + (size_t)c0 * 4);
    #pragma unroll
    for (int q = 0; q < 4; ++q) {
      const short8v v = wp[q];
      #pragma unroll
      for (int e = 0; e < 8; ++e) wreg[q * 8 + e] = bf2f(v[e]);
    }
    const short8v bv = *(const short8v*)((const short*)cb + c0);
    #pragma unroll
    for (int j = 0; j < 8; ++j) bias[j] = bf2f(bv[j]);
  }

  float xw[4][8];
  #pragma unroll
  for (int k = 0; k < 3; ++k) {
    if (t0 + k - 3 >= 0) {
      const short8v v = *(const short8v*)&xz[(size_t)(r0 + k - 3) * 4096 + c0];
      #pragma unroll
      for (int j = 0; j < 8; ++j) xw[k][j] = bf2f(v[j]);
    } else {
      #pragma unroll
      for (int j = 0; j < 8; ++j) xw[k][j] = 0.f;
    }
  }
  #pragma unroll
  for (int t = 0; t < CONV_RPB; ++t) {
    const int row = r0 + t;
    const short8v v = *(const short8v*)&xz[(size_t)row * 4096 + c0];
    #pragma unroll
    for (int j = 0; j < 8; ++j) xw[3][j] = bf2f(v[j]);
    short8v ov;
    #pragma unroll
    for (int j = 0; j < 8; ++j) {
      float a = bias[j];
      #pragma unroll
      for (int k = 0; k < 4; ++k) a += xw[k][j] * wreg[j * 4 + k];
      ov[j] = f2bf(a / (1.f + __expf(-a)));
    }
    *(short8v*)&xc[(size_t)row * D_INNER + c0] = ov;
    #pragma unroll
    for (int k = 0; k < 3; ++k)
      #pragma unroll
      for (int j = 0; j < 8; ++j) xw[k][j] = xw[k + 1][j];
  }
}

// -------- chunk-parallel scan, per-thread 16-state, row-major inputs --------
// A_log = log(arange(1..17)) broadcast => Ac[s] = -(s+1): exp(Ac[s]*dt) = e1^(s+1),
// e1 = exp2(Ac[0]*log2e*dt). One trans op + 15 muls replaces 16 trans + 16 muls.
// Runtime pattern check (uniform branch) falls back to generic exp path.
// XCD-chunk block swizzle: adjacent 16-ch slabs share 64B lines; putting slab
// pairs on the same XCD halves L2-miss line duplication.
#define SCAN_CK 64
#define SCAN_ST 32
__global__ __launch_bounds__(1024, 4) void scan_kernel(
    const short* __restrict__ dtb, const short* __restrict__ xcv,
    const float* __restrict__ Bm, const float* __restrict__ Cm,
    short* __restrict__ xzb, const void* __restrict__ A_log,
    const void* __restrict__ Dv, const int* __restrict__ flag) {
  const int f32 = *flag;
  const int tid = threadIdx.x;
  const int dl = tid & 15;
  const int ck = tid >> 4;
  // bijective XCD-chunk swizzle over 256 blocks: s = (d&7)<<5 | d>>3
  const int d = blockIdx.x;
  const int s_ = ((d & 7) << 5) | (d >> 3);
  const int bx = s_ & 127;
  const int b = s_ >> 7;
  const int di = (bx << 4) + dl;
  const int r0 = (b << 11) + ck * SCAN_ST;       // global row (b,t0)

  const short* dtp = dtb + (size_t)r0 * 2048 + di;
  const short* xcp = xcv + (size_t)r0 * 2048 + di;
  const float* bmp = Bm + (size_t)r0 * 16;
  const float* cmp = Cm + (size_t)r0 * 16;
  const short* zp = xzb + (size_t)r0 * 4096 + 2048 + di;
  short* yp = xzb + (size_t)r0 * 4096 + di;

  float Ac[16];
  #pragma unroll
  for (int s = 0; s < 16; ++s)
    Ac[s] = -__expf(lde(A_log, (size_t)di * 16 + s, f32));
  const float Dval = lde(Dv, di, f32);

  // pattern check: Ac[s] == (s+1)*Ac[0] (within tolerance). Uniform in practice.
  bool pat = true;
  #pragma unroll
  for (int s = 1; s < 16; ++s)
    pat = pat && (fabsf(Ac[s] - (float)(s + 1) * Ac[0]) <= fabsf(Ac[s]) * 1e-3f + 1e-6f);
  const float al = Ac[0] * 1.442695041f;   // log2(e) * Ac[0]

#define POWCHAIN(es, e1) do {                                        \
    es[0] = (e1);                                                    \
    es[1] = es[0] * es[0];  es[2] = es[1] * es[0];                   \
    es[3] = es[1] * es[1];  es[4] = es[3] * es[0];                   \
    es[5] = es[3] * es[1];  es[6] = es[3] * es[2];                   \
    es[7] = es[3] * es[3];  es[8] = es[7] * es[0];                   \
    es[9] = es[7] * es[1];  es[10] = es[7] * es[2];                  \
    es[11] = es[7] * es[3]; es[12] = es[7] * es[4];                  \
    es[13] = es[7] * es[5]; es[14] = es[7] * es[6];                  \
    es[15] = es[7] * es[7]; } while (0)

  float h[16];
  #pragma unroll
  for (int s = 0; s < 16; ++s) h[s] = 0.f;
  float sdt = 0.f;

  // pass 1: local scan (h0=0), track sum(dt)
  if (pat) {
    #pragma unroll 2
    for (int t = 0; t < SCAN_ST; ++t) {
      const float dt = bf2f(dtp[(size_t)t * 2048]);
      const float xc = bf2f(xcp[(size_t)t * 2048]);
      const float4v b0 = *(const float4v*)&bmp[t * 16];
      const float4v b1 = *(const float4v*)&bmp[t * 16 + 4];
      const float4v b2 = *(const float4v*)&bmp[t * 16 + 8];
      const float4v b3 = *(const float4v*)&bmp[t * 16 + 12];
      sdt += dt;
      const float u = xc * dt;
      float es[16];
      POWCHAIN(es, exp2f(al * dt));
      #pragma unroll
      for (int s = 0; s < 4; ++s) {
        h[s]      = h[s]      * es[s]      + u * b0[s];
        h[s + 4]  = h[s + 4]  * es[s + 4]  + u * b1[s];
        h[s + 8]  = h[s + 8]  * es[s + 8]  + u * b2[s];
        h[s + 12] = h[s + 12] * es[s + 12] + u * b3[s];
      }
    }
  } else {
    #pragma unroll 2
    for (int t = 0; t < SCAN_ST; ++t) {
      const float dt = bf2f(dtp[(size_t)t * 2048]);
      const float xc = bf2f(xcp[(size_t)t * 2048]);
      const float4v b0 = *(const float4v*)&bmp[t * 16];
      const float4v b1 = *(const float4v*)&bmp[t * 16 + 4];
      const float4v b2 = *(const float4v*)&bmp[t * 16 + 8];
      const float4v b3 = *(const float4v*)&bmp[t * 16 + 12];
      sdt += dt;
      const float u = xc * dt;
      #pragma unroll
      for (int s = 0; s < 4; ++s) {
        h[s]      = h[s]      * __expf(Ac[s]      * dt) + u * b0[s];
        h[s + 4]  = h[s + 4]  * __expf(Ac[s + 4]  * dt) + u * b1[s];
        h[s + 8]  = h[s + 8]  * __expf(Ac[s + 8]  * dt) + u * b2[s];
        h[s + 12] = h[s + 12] * __expf(Ac[s + 12] * dt) + u * b3[s];
      }
    }
  }

  __shared__ float sdt_s[SCAN_CK][16];
  __shared__ float hc_s[SCAN_CK][16][17];    // hend in, hstart out (in-place)
  sdt_s[ck][dl] = sdt;
  #pragma unroll
  for (int s = 0; s < 16; ++s) hc_s[ck][dl][s] = h[s];
  __syncthreads();
  if (tid < 256) {
    const int s = tid >> 4;
    const float Acs = -__expf(lde(A_log, (size_t)di * 16 + s, f32));
    float hs = 0.f;
    #pragma unroll 4
    for (int c = 0; c < SCAN_CK; ++c) {
      const float hend = hc_s[c][dl][s];
      hc_s[c][dl][s] = hs;                   // hstart for chunk c
      hs = __expf(Acs * sdt_s[c][dl]) * hs + hend;
    }
  }
  __syncthreads();
  #pragma unroll
  for (int s = 0; s < 16; ++s) h[s] = hc_s[ck][dl][s];

  // pass 2: rescan with true h_start, emit y (coalesced across dl)
  if (pat) {
    #pragma unroll 2
    for (int t = 0; t < SCAN_ST; ++t) {
      const float dt = bf2f(dtp[(size_t)t * 2048]);
      const float xc = bf2f(xcp[(size_t)t * 2048]);
      const float4v b0 = *(const float4v*)&bmp[t * 16];
      const float4v b1 = *(const float4v*)&bmp[t * 16 + 4];
      const float4v b2 = *(const float4v*)&bmp[t * 16 + 8];
      const float4v b3 = *(const float4v*)&bmp[t * 16 + 12];
      const float4v c0 = *(const float4v*)&cmp[t * 16];
      const float4v c1 = *(const float4v*)&cmp[t * 16 + 4];
      const float4v c2 = *(const float4v*)&cmp[t * 16 + 8];
      const float4v c3 = *(const float4v*)&cmp[t * 16 + 12];
      const float u = xc * dt;
      float es[16];
      POWCHAIN(es, exp2f(al * dt));
      float p0 = 0.f, p1 = 0.f, p2 = 0.f, p3 = 0.f;
      #pragma unroll
      for (int s = 0; s < 4; ++s) {
        h[s]      = h[s]      * es[s]      + u * b0[s];
        h[s + 4]  = h[s + 4]  * es[s + 4]  + u * b1[s];
        h[s + 8]  = h[s + 8]  * es[s + 8]  + u * b2[s];
        h[s + 12] = h[s + 12] * es[s + 12] + u * b3[s];
        p0 += h[s] * c0[s];
        p1 += h[s + 4] * c1[s];
        p2 += h[s + 8] * c2[s];
        p3 += h[s + 12] * c3[s];
      }
      const float p = (p0 + p1) + (p2 + p3);
      const float z = bf2f(zp[(size_t)t * 4096]);
      const float sz = z * __builtin_amdgcn_rcpf(1.f + __expf(-z));
      yp[(size_t)t * 4096] = f2bf((p + xc * Dval) * sz);
    }
  } else {
    #pragma unroll 2
    for (int t = 0; t < SCAN_ST; ++t) {
      const float dt = bf2f(dtp[(size_t)t * 2048]);
      const float xc = bf2f(xcp[(size_t)t * 2048]);
      const float4v b0 = *(const float4v*)&bmp[t * 16];
      const float4v b1 = *(const float4v*)&bmp[t * 16 + 4];
      const float4v b2 = *(const float4v*)&bmp[t * 16 + 8];
      const float4v b3 = *(const float4v*)&bmp[t * 16 + 12];
      const float4v c0 = *(const float4v*)&cmp[t * 16];
      const float4v c1 = *(const float4v*)&cmp[t * 16 + 4];
      const float4v c2 = *(const float4v*)&cmp[t * 16 + 8];
      const float4v c3 = *(const float4v*)&cmp[t * 16 + 12];
      const float u = xc * dt;
      float p0 = 0.f, p1 = 0.f, p2 = 0.f, p3 = 0.f;
      #pragma unroll
      for (int s = 0; s < 4; ++s) {
        h[s]      = h[s]      * __expf(Ac[s]      * dt) + u * b0[s];
        h[s + 4]  = h[s + 4]  * __expf(Ac[s + 4]  * dt) + u * b1[s];
        h[s + 8]  = h[s + 8]  * __expf(Ac[s + 8]  * dt) + u * b2[s];
        h[s + 12] = h[s + 12] * __expf(Ac[s + 12] * dt) + u * b3[s];
        p0 += h[s] * c0[s];
        p1 += h[s + 4] * c1[s];
        p2 += h[s + 8] * c2[s];
        p3 += h[s + 12] * c3[s];
      }
      const float p = (p0 + p1) + (p2 + p3);
      const float z = bf2f(zp[(size_t)t * 4096]);
      const float sz = z * __builtin_amdgcn_rcpf(1.f + __expf(-z));
      yp[(size_t)t * 4096] = f2bf((p + xc * Dval) * sz);
    }
  }
#undef POWCHAIN
}

// -------- launch ----------
extern "C" void kernel_launch(void* const* d_in, const int* in_sizes, int n_in,
                              void* d_out, int out_size, void* d_ws, size_t ws_size,
                              hipStream_t stream) {
  const void* x      = d_in[0];
  const void* norm_w = d_in[1];
  const void* norm_b = d_in[2];
  const void* W_in   = d_in[3];
  const void* conv_w = d_in[4];
  const void* conv_b = d_in[5];
  const void* W_dt   = d_in[6];
  const void* b_dt   = d_in[7];
  const void* W_B    = d_in[8];
  const void* W_C    = d_in[9];
  const void* Dv     = d_in[10];
  const void* A_log  = d_in[11];
  const void* W_out  = d_in[12];

  char* ws = (char*)d_ws;
  const size_t MB = (size_t)1 << 20;
  short* wcvt = (short*)(ws);                 //  0-20.5 MB: W_in | [W_dt;W_B;W_C;pad] | W_out
  short* wbuf = wcvt;
  short* wcat = wcvt + WIN_N;                 // 2176 x 2048 bf16
  short* wout = wcvt + WIN_N + WCAT_N;
  int*   flag = (int*)(ws + 21 * MB - 256);
  short* xzb  = (short*)(ws + 21 * MB);       // 21-53 MB [4096 x 4096] (z kept; y overwrites x_part)
  short* xcv  = (short*)(ws + 53 * MB);       // 53-69 MB xc row-major
  short* xn   = (short*)(ws + 69 * MB);       //  8 MB (aliased with dtb)
  short* dtb  = (short*)(ws + 69 * MB);       // 69-85 MB dt row-major [(b,t)][di]
  float* Bm   = (float*)(ws + 85 * MB);       // 256 KB [(b,t)][s]
  float* Cm   = Bm + (size_t)NROWS * 16;      // 256 KB

  probe_kernel<<<1, 64, 0, stream>>>((const unsigned int*)x, flag);
  cvt_kernel<<<5248, 256, 0, stream>>>(W_in, W_dt, W_B, W_C, W_out, wcvt, flag);
  ln_kernel<<<NROWS, 256, 0, stream>>>(x, norm_w, norm_b, xn, flag);
  // gemm0: BM=256/BN=128, grid (32,16), 512 blocks (R4/R5 proven config)
  gemm_bt<0, 256><<<dim3(32, 16), 512, 0, stream>>>(xn, 1024, wbuf, xzb, 4096, 1024, nullptr, nullptr, nullptr, flag);
  conv_silu<<<NROWS / CONV_RPB, 256, 0, stream>>>(xzb, conv_w, conv_b, xcv, flag);
  // gemm1: R5 quad-buffer config + fused Bm/Cm: N=2176 -> grid (17,32)=544 blocks
  gemm_bt<1, 128><<<dim3(17, 32), 256, 0, stream>>>(xcv, 2048, wcat, dtb, 2176, 2048, b_dt, Bm, Cm, flag);
  scan_kernel<<<256, 1024, 0, stream>>>(dtb, xcv, Bm, Cm, xzb, A_log, Dv, flag);
  // gemm2: R5 quad-buffer config, grid (8,32)=256 blocks
  gemm_bt<2, 128><<<dim3(8, 32), 256, 0, stream>>>(xzb, 4096, wout, d_out, 1024, 2048, x, nullptr, nullptr, flag);
}

// Round 9
// 373.855 us; speedup vs baseline: 1.1030x; 1.1030x over previous
//
#include <hip/hip_runtime.h>
#include <cstdint>
#include <cstddef>

#define D_MODEL 1024
#define D_INNER 2048
#define D_STATE 16
#define SEQ     2048
#define NROWS   4096   // B * SEQ

typedef short short4v __attribute__((ext_vector_type(4)));
typedef short short8v __attribute__((ext_vector_type(8)));
typedef float float4v __attribute__((ext_vector_type(4)));

__device__ __forceinline__ float bf2f(short u) {
  union { unsigned int i; float f; } v;
  v.i = ((unsigned int)(unsigned short)u) << 16;
  return v.f;
}
__device__ __forceinline__ short f2bf(float f) {
  union { float f; unsigned int i; } v; v.f = f;
  unsigned int r = v.i + 0x7FFFu + ((v.i >> 16) & 1u);  // RNE
  return (short)(r >> 16);
}
// dtype-flagged scalar load: f32==1 -> float*, else bf16
__device__ __forceinline__ float lde(const void* p, size_t i, int f32) {
  return f32 ? ((const float*)p)[i] : bf2f(((const short*)p)[i]);
}
__device__ __forceinline__ void async16(short* lds, const short* g) {
  __builtin_amdgcn_global_load_lds(
      (const __attribute__((address_space(1))) unsigned int*)g,
      (__attribute__((address_space(3))) unsigned int*)lds, 16, 0, 0);
}

// -------- dtype probe ----------
__global__ __launch_bounds__(64) void probe_kernel(const unsigned int* __restrict__ xw,
                                                   int* __restrict__ flag) {
  int cnt = 0;
  for (int i = threadIdx.x; i < 1024; i += 64) {
    unsigned e = (xw[i] >> 7) & 0xFFu;
    cnt += (e >= 100u && e <= 150u) ? 1 : 0;
  }
  #pragma unroll
  for (int o = 32; o >= 1; o >>= 1) cnt += __shfl_xor(cnt, o);
  if (threadIdx.x == 0) *flag = (cnt < 614) ? 1 : 0;   // 1 => fp32 inputs
}

// -------- convert weights to bf16: [W_in | W_dt;W_B;W_C;pad | W_out] ----------
#define WIN_N  4194304u                 // 4096*1024
#define WDT_N  4194304u                 // 2048*2048
#define WBC_N  32768u                   // 16*2048
#define WPAD_N 196608u                  // 96*2048  (zero pad rows 2080..2175)
#define WCAT_N (WDT_N + 2u*WBC_N + WPAD_N)   // 2176*2048 = 4456448
#define WOUT_N 2097152u                 // 1024*2048
__global__ __launch_bounds__(256) void cvt_kernel(
    const void* __restrict__ Win, const void* __restrict__ Wdt,
    const void* __restrict__ WBp, const void* __restrict__ WCp,
    const void* __restrict__ Wout, short* __restrict__ dst,
    const int* __restrict__ flag) {
  const int f32 = *flag;
  const size_t i = ((size_t)blockIdx.x * 256 + threadIdx.x) * 8;
  const void* src = nullptr; size_t off = 0; bool zero = false;
  if (i < WIN_N) { src = Win; off = i; }
  else {
    size_t j = i - WIN_N;
    if (j < WDT_N) { src = Wdt; off = j; }
    else {
      j -= WDT_N;
      if (j < WBC_N) { src = WBp; off = j; }
      else {
        j -= WBC_N;
        if (j < WBC_N) { src = WCp; off = j; }
        else {
          j -= WBC_N;
          if (j < WPAD_N) zero = true;
          else { src = Wout; off = j - WPAD_N; }
        }
      }
    }
  }
  short8v o;
  if (zero) {
    #pragma unroll
    for (int j = 0; j < 8; ++j) o[j] = 0;
  } else if (f32) {
    const float* s = (const float*)src + off;
    #pragma unroll
    for (int j = 0; j < 8; ++j) o[j] = f2bf(s[j]);
  } else {
    o = *(const short8v*)((const short*)src + off);
  }
  *(short8v*)&dst[i] = o;
}

// -------- LayerNorm ----------
__global__ __launch_bounds__(256) void ln_kernel(
    const void* __restrict__ x, const void* __restrict__ w,
    const void* __restrict__ bb, short* __restrict__ xn,
    const int* __restrict__ flag) {
  const int f32 = *flag;
  const int row = blockIdx.x;
  const int tid = threadIdx.x;
  float v0, v1, v2, v3;
  if (f32) {
    float4v xv = ((const float4v*)((const float*)x + (size_t)row * D_MODEL))[tid];
    v0 = xv[0]; v1 = xv[1]; v2 = xv[2]; v3 = xv[3];
  } else {
    short4v xv = *(const short4v*)&((const short*)x)[(size_t)row * D_MODEL + tid * 4];
    v0 = bf2f(xv[0]); v1 = bf2f(xv[1]); v2 = bf2f(xv[2]); v3 = bf2f(xv[3]);
  }
  float s = v0 + v1 + v2 + v3;
  float q = v0*v0 + v1*v1 + v2*v2 + v3*v3;
  #pragma unroll
  for (int off = 32; off >= 1; off >>= 1) {
    s += __shfl_xor(s, off);
    q += __shfl_xor(q, off);
  }
  __shared__ float red[8];
  const int wid = tid >> 6;
  if ((tid & 63) == 0) { red[wid] = s; red[4 + wid] = q; }
  __syncthreads();
  s = red[0] + red[1] + red[2] + red[3];
  q = red[4] + red[5] + red[6] + red[7];
  const float mu = s * (1.f / 1024.f);
  const float var = q * (1.f / 1024.f) - mu * mu;
  const float rstd = rsqrtf(var + 1e-5f);
  short4v ov;
  #pragma unroll
  for (int j = 0; j < 4; ++j) {
    const float vj = (j == 0) ? v0 : (j == 1) ? v1 : (j == 2) ? v2 : v3;
    const float o = (vj - mu) * rstd * lde(w, tid * 4 + j, f32) + lde(bb, tid * 4 + j, f32);
    ov[j] = f2bf(o);
  }
  *(short4v*)&xn[(size_t)row * D_MODEL + tid * 4] = ov;
}

// -------- MFMA GEMM: C[m,n] = sum_k A[m,k]*B[n,k]; A row stride lda, B stride K
// Tile BM x 128. BM=256: 512 thr, double-buffer, vmcnt(3) distance-1 (R4 cfg).
// BM=128: 256 thr, QUAD-buffer ring, distance-3 vmcnt(12) steady state (R5 cfg
// -- measured best: 85.2us on the dt GEMM at grid (16,32)=512 blocks, 2 blk/CU).
// GRID RULE [measured R0/R8]: grid must sit at/just under a multiple of
// residency(2/CU)*256 = 512; 544 blocks cost +49% (tail round).
// LDS chunk-XOR swizzle: slot chunk c of row r holds global chunk c^((r>>1)&3);
// applied on global SOURCE at stage time and on ds_read addr at use.
// MODE 0: bf16 store row-major (stride N)
// MODE 1: softplus(acc+bias[col]) bf16, stride 2048 (N=2048 -> cols < 2048)
// MODE 2: acc+resid -> dtype-flagged store (stride N)
template <int MODE, int BM>
__global__ __launch_bounds__(2 * BM) void gemm_bt(
    const short* __restrict__ A, int lda, const short* __restrict__ B,
    void* __restrict__ Cv, int N, int K, const void* __restrict__ aux,
    const int* __restrict__ flag) {
  constexpr int NBUF = (BM == 256) ? 2 : 4;
  __shared__ __align__(16) short As[NBUF][BM * 32];
  __shared__ __align__(16) short Bs[NBUF][128 * 32];
  const int f32 = *flag;
  const int tid = threadIdx.x;
  const int bm = blockIdx.y * BM;
  const int bn = blockIdx.x << 7;
  const int wid = tid >> 6;
  const int lane = tid & 63;
  const int wm = (wid >> 1) << 6;
  const int wn = (wid & 1) << 6;

  float4v acc[4][4];
  #pragma unroll
  for (int i = 0; i < 4; ++i)
    #pragma unroll
    for (int j = 0; j < 4; ++j) acc[i][j] = (float4v){0.f, 0.f, 0.f, 0.f};

  const int srow = tid >> 2;            // 0 .. BM/2-1
  const int scol = (((tid & 3) ^ ((tid >> 3) & 3)) << 3);   // source chunk-XOR
  const short* ga = A + (size_t)(bm + srow) * lda + scol;
  const short* gb = B + (size_t)(bn + srow) * K + scol;   // srow < 128 needed for BM=256 single-DMA B
  const size_t astep = (size_t)(BM / 2) * lda;
  const size_t bstep = (size_t)64 * K;

  const int fr = lane & 15;
  const int fq = (((lane >> 4) ^ ((lane >> 1) & 3)) << 3);  // read chunk-XOR

#define STAGE(Ad, Bd, kk) do {                              \
    async16(&Ad[tid * 8], ga + (kk));                       \
    async16(&Ad[BM * 16 + tid * 8], ga + astep + (kk));     \
    if (BM == 256) {                                        \
      async16(&Bd[tid * 8], gb + (kk));                     \
    } else {                                                \
      async16(&Bd[tid * 8], gb + (kk));                     \
      async16(&Bd[2048 + tid * 8], gb + bstep + (kk));      \
    } } while (0)
#define VMW(NW) __builtin_amdgcn_s_waitcnt(0x3FF0 | (NW))
#define BAR __builtin_amdgcn_s_barrier()

  auto compute = [&](const short* Asrc, const short* Bsrc) {
    short8v af[4], bfv[4];
    #pragma unroll
    for (int i = 0; i < 4; ++i)
      af[i] = *(const short8v*)&Asrc[(wm + i * 16 + fr) * 32 + fq];
    #pragma unroll
    for (int j = 0; j < 4; ++j)
      bfv[j] = *(const short8v*)&Bsrc[(wn + j * 16 + fr) * 32 + fq];
    #pragma unroll
    for (int i = 0; i < 4; ++i)
      #pragma unroll
      for (int j = 0; j < 4; ++j)
        acc[i][j] = __builtin_amdgcn_mfma_f32_16x16x32_bf16(af[i], bfv[j], acc[i][j], 0, 0, 0);
  };

  const int nk = K >> 5;   // multiple of 4 for all our K
  if constexpr (BM == 128) {
    // quad-buffer ring, prefetch distance 3 (3 stages x 4 DMAs in flight)
    STAGE(As[0], Bs[0], 0);
    STAGE(As[1], Bs[1], 32);
    STAGE(As[2], Bs[2], 64);
    int c = 0;
    for (; c + 4 < nk; c += 4) {
      STAGE(As[3], Bs[3], (c + 3) << 5); VMW(12); BAR; compute(As[0], Bs[0]); BAR;
      STAGE(As[0], Bs[0], (c + 4) << 5); VMW(12); BAR; compute(As[1], Bs[1]); BAR;
      STAGE(As[1], Bs[1], (c + 5) << 5); VMW(12); BAR; compute(As[2], Bs[2]); BAR;
      STAGE(As[2], Bs[2], (c + 6) << 5); VMW(12); BAR; compute(As[3], Bs[3]); BAR;
    }
    // c == nk-4: drain 12 -> 8 -> 4 -> 0
    STAGE(As[3], Bs[3], (nk - 1) << 5); VMW(12); BAR; compute(As[0], Bs[0]); BAR;
    VMW(8); BAR; compute(As[1], Bs[1]); BAR;
    VMW(4); BAR; compute(As[2], Bs[2]); BAR;
    VMW(0); BAR; compute(As[3], Bs[3]);
  } else {
    STAGE(As[0], Bs[0], 0);
    for (int k2 = 0; k2 < nk; k2 += 2) {
      STAGE(As[1], Bs[1], (k2 + 1) << 5);
      VMW(3);
      BAR;
      compute(As[0], Bs[0]);
      BAR;
      if (k2 + 2 < nk) {
        STAGE(As[0], Bs[0], (k2 + 2) << 5);
        VMW(3);
      } else {
        VMW(0);
      }
      BAR;
      compute(As[1], Bs[1]);
      BAR;
    }
  }
#undef STAGE
#undef VMW
#undef BAR

  const int er = (lane >> 4) << 2;
  const int ec = lane & 15;
  #pragma unroll
  for (int i = 0; i < 4; ++i) {
    #pragma unroll
    for (int j = 0; j < 4; ++j) {
      const int gcol = bn + wn + j * 16 + ec;
      #pragma unroll
      for (int r = 0; r < 4; ++r) {
        const int grow = bm + wm + i * 16 + er + r;
        float v = acc[i][j][r];
        if (MODE == 1) {
          v += lde(aux, gcol, f32);
          v = (v > 15.f) ? v : log1pf(__expf(v));
          ((short*)Cv)[(size_t)grow * 2048 + gcol] = f2bf(v);
        } else {
          const size_t idx = (size_t)grow * N + gcol;
          if (MODE == 2) {
            v += lde(aux, idx, f32);
            if (f32) ((float*)Cv)[idx] = v;
            else     ((short*)Cv)[idx] = f2bf(v);
          } else {
            ((short*)Cv)[idx] = f2bf(v);
          }
        }
      }
    }
  }
}

// -------- Bm/Cm: out[row][n] = sum_k xcv[row][k] * W[n][k]
// W = wcat rows 2048..2079 (W_B 16 rows, then W_C 16 rows), bf16.
// 256 blocks x 256 threads; block handles 16 rows; 4 waves split K, LDS-reduce.
__global__ __launch_bounds__(256) void bc_kernel(
    const short* __restrict__ xcv, const short* __restrict__ wbc,
    float* __restrict__ Bmo, float* __restrict__ Cmo) {
  const int tid = threadIdx.x;
  const int w = tid >> 6;          // 0..3
  const int lane = tid & 63;
  const int fr = lane & 15;
  const int hi = lane >> 4;
  const int r0 = blockIdx.x << 4;
  const short* ap  = xcv + (size_t)(r0 + fr) * 2048 + hi * 8;
  const short* b0p = wbc + (size_t)fr * 2048 + hi * 8;          // W_B rows
  const short* b1p = wbc + (size_t)(16 + fr) * 2048 + hi * 8;   // W_C rows
  float4v acc0 = (float4v){0.f, 0.f, 0.f, 0.f};
  float4v acc1 = (float4v){0.f, 0.f, 0.f, 0.f};
  #pragma unroll 4
  for (int k = w * 32; k < 2048; k += 128) {
    const short8v af  = *(const short8v*)(ap + k);
    const short8v bf0 = *(const short8v*)(b0p + k);
    const short8v bf1 = *(const short8v*)(b1p + k);
    acc0 = __builtin_amdgcn_mfma_f32_16x16x32_bf16(af, bf0, acc0, 0, 0, 0);
    acc1 = __builtin_amdgcn_mfma_f32_16x16x32_bf16(af, bf1, acc1, 0, 0, 0);
  }
  __shared__ float red[3][64][8];
  if (w) {
    #pragma unroll
    for (int r = 0; r < 4; ++r) {
      red[w - 1][lane][r]     = acc0[r];
      red[w - 1][lane][4 + r] = acc1[r];
    }
  }
  __syncthreads();
  if (w == 0) {
    #pragma unroll
    for (int c = 0; c < 3; ++c)
      #pragma unroll
      for (int r = 0; r < 4; ++r) {
        acc0[r] += red[c][lane][r];
        acc1[r] += red[c][lane][4 + r];
      }
    const int er = hi << 2;
    const int ec = fr;
    #pragma unroll
    for (int r = 0; r < 4; ++r) {
      Bmo[(size_t)(r0 + er + r) * 16 + ec] = acc0[r];
      Cmo[(size_t)(r0 + er + r) * 16 + ec] = acc1[r];
    }
  }
}

// -------- causal depthwise conv (K=4) + SiLU, 8 rows/block, sliding window ----
#define CONV_RPB 8
__global__ __launch_bounds__(256) void conv_silu(
    const short* __restrict__ xz, const void* __restrict__ cw,
    const void* __restrict__ cb, short* __restrict__ xc,
    const int* __restrict__ flag) {
  const int f32 = *flag;
  const int r0 = blockIdx.x * CONV_RPB;
  const int c0 = threadIdx.x << 3;
  const int t0 = r0 & (SEQ - 1);     // 2048 % CONV_RPB == 0: no block straddles a batch boundary

  float wreg[32], bias[8];
  if (f32) {
    const float4v* wp = (const float4v*)((const float*)cw + (size_t)c0 * 4);
    #pragma unroll
    for (int q = 0; q < 8; ++q) {
      const float4v v = wp[q];
      #pragma unroll
      for (int k = 0; k < 4; ++k) wreg[q * 4 + k] = v[k];
    }
    const float4v* bp = (const float4v*)((const float*)cb + c0);
    const float4v b0 = bp[0], b1 = bp[1];
    #pragma unroll
    for (int j = 0; j < 4; ++j) { bias[j] = b0[j]; bias[4 + j] = b1[j]; }
  } else {
    const short8v* wp = (const short8v*)((const short*)cw + (size_t)c0 * 4);
    #pragma unroll
    for (int q = 0; q < 4; ++q) {
      const short8v v = wp[q];
      #pragma unroll
      for (int e = 0; e < 8; ++e) wreg[q * 8 + e] = bf2f(v[e]);
    }
    const short8v bv = *(const short8v*)((const short*)cb + c0);
    #pragma unroll
    for (int j = 0; j < 8; ++j) bias[j] = bf2f(bv[j]);
  }

  float xw[4][8];
  #pragma unroll
  for (int k = 0; k < 3; ++k) {
    if (t0 + k - 3 >= 0) {
      const short8v v = *(const short8v*)&xz[(size_t)(r0 + k - 3) * 4096 + c0];
      #pragma unroll
      for (int j = 0; j < 8; ++j) xw[k][j] = bf2f(v[j]);
    } else {
      #pragma unroll
      for (int j = 0; j < 8; ++j) xw[k][j] = 0.f;
    }
  }
  #pragma unroll
  for (int t = 0; t < CONV_RPB; ++t) {
    const int row = r0 + t;
    const short8v v = *(const short8v*)&xz[(size_t)row * 4096 + c0];
    #pragma unroll
    for (int j = 0; j < 8; ++j) xw[3][j] = bf2f(v[j]);
    short8v ov;
    #pragma unroll
    for (int j = 0; j < 8; ++j) {
      float a = bias[j];
      #pragma unroll
      for (int k = 0; k < 4; ++k) a += xw[k][j] * wreg[j * 4 + k];
      ov[j] = f2bf(a / (1.f + __expf(-a)));
    }
    *(short8v*)&xc[(size_t)row * D_INNER + c0] = ov;
    #pragma unroll
    for (int k = 0; k < 3; ++k)
      #pragma unroll
      for (int j = 0; j < 8; ++j) xw[k][j] = xw[k + 1][j];
  }
}

// -------- chunk-parallel scan, per-thread 16-state, row-major inputs --------
// A_log = log(arange(1..17)) broadcast => Ac[s] = -(s+1): exp(Ac[s]*dt) = e1^(s+1),
// e1 = exp2(Ac[0]*log2e*dt). One trans op + 15 muls replaces 16 trans + 16 muls.
// Runtime pattern check (uniform branch) falls back to generic exp path.
// XCD-chunk block swizzle: adjacent 16-ch slabs share 64B lines; putting slab
// pairs on the same XCD halves L2-miss line duplication.
#define SCAN_CK 64
#define SCAN_ST 32
__global__ __launch_bounds__(1024, 4) void scan_kernel(
    const short* __restrict__ dtb, const short* __restrict__ xcv,
    const float* __restrict__ Bm, const float* __restrict__ Cm,
    short* __restrict__ xzb, const void* __restrict__ A_log,
    const void* __restrict__ Dv, const int* __restrict__ flag) {
  const int f32 = *flag;
  const int tid = threadIdx.x;
  const int dl = tid & 15;
  const int ck = tid >> 4;
  // bijective XCD-chunk swizzle over 256 blocks: s = (d&7)<<5 | d>>3
  const int d = blockIdx.x;
  const int s_ = ((d & 7) << 5) | (d >> 3);
  const int bx = s_ & 127;
  const int b = s_ >> 7;
  const int di = (bx << 4) + dl;
  const int r0 = (b << 11) + ck * SCAN_ST;       // global row (b,t0)

  const short* dtp = dtb + (size_t)r0 * 2048 + di;
  const short* xcp = xcv + (size_t)r0 * 2048 + di;
  const float* bmp = Bm + (size_t)r0 * 16;
  const float* cmp = Cm + (size_t)r0 * 16;
  const short* zp = xzb + (size_t)r0 * 4096 + 2048 + di;
  short* yp = xzb + (size_t)r0 * 4096 + di;

  float Ac[16];
  #pragma unroll
  for (int s = 0; s < 16; ++s)
    Ac[s] = -__expf(lde(A_log, (size_t)di * 16 + s, f32));
  const float Dval = lde(Dv, di, f32);

  // pattern check: Ac[s] == (s+1)*Ac[0] (within tolerance). Uniform in practice.
  bool pat = true;
  #pragma unroll
  for (int s = 1; s < 16; ++s)
    pat = pat && (fabsf(Ac[s] - (float)(s + 1) * Ac[0]) <= fabsf(Ac[s]) * 1e-3f + 1e-6f);
  const float al = Ac[0] * 1.442695041f;   // log2(e) * Ac[0]

#define POWCHAIN(es, e1) do {                                        \
    es[0] = (e1);                                                    \
    es[1] = es[0] * es[0];  es[2] = es[1] * es[0];                   \
    es[3] = es[1] * es[1];  es[4] = es[3] * es[0];                   \
    es[5] = es[3] * es[1];  es[6] = es[3] * es[2];                   \
    es[7] = es[3] * es[3];  es[8] = es[7] * es[0];                   \
    es[9] = es[7] * es[1];  es[10] = es[7] * es[2];                  \
    es[11] = es[7] * es[3]; es[12] = es[7] * es[4];                  \
    es[13] = es[7] * es[5]; es[14] = es[7] * es[6];                  \
    es[15] = es[7] * es[7]; } while (0)

  float h[16];
  #pragma unroll
  for (int s = 0; s < 16; ++s) h[s] = 0.f;
  float sdt = 0.f;

  // pass 1: local scan (h0=0), track sum(dt)
  if (pat) {
    #pragma unroll 2
    for (int t = 0; t < SCAN_ST; ++t) {
      const float dt = bf2f(dtp[(size_t)t * 2048]);
      const float xc = bf2f(xcp[(size_t)t * 2048]);
      const float4v b0 = *(const float4v*)&bmp[t * 16];
      const float4v b1 = *(const float4v*)&bmp[t * 16 + 4];
      const float4v b2 = *(const float4v*)&bmp[t * 16 + 8];
      const float4v b3 = *(const float4v*)&bmp[t * 16 + 12];
      sdt += dt;
      const float u = xc * dt;
      float es[16];
      POWCHAIN(es, exp2f(al * dt));
      #pragma unroll
      for (int s = 0; s < 4; ++s) {
        h[s]      = h[s]      * es[s]      + u * b0[s];
        h[s + 4]  = h[s + 4]  * es[s + 4]  + u * b1[s];
        h[s + 8]  = h[s + 8]  * es[s + 8]  + u * b2[s];
        h[s + 12] = h[s + 12] * es[s + 12] + u * b3[s];
      }
    }
  } else {
    #pragma unroll 2
    for (int t = 0; t < SCAN_ST; ++t) {
      const float dt = bf2f(dtp[(size_t)t * 2048]);
      const float xc = bf2f(xcp[(size_t)t * 2048]);
      const float4v b0 = *(const float4v*)&bmp[t * 16];
      const float4v b1 = *(const float4v*)&bmp[t * 16 + 4];
      const float4v b2 = *(const float4v*)&bmp[t * 16 + 8];
      const float4v b3 = *(const float4v*)&bmp[t * 16 + 12];
      sdt += dt;
      const float u = xc * dt;
      #pragma unroll
      for (int s = 0; s < 4; ++s) {
        h[s]      = h[s]      * __expf(Ac[s]      * dt) + u * b0[s];
        h[s + 4]  = h[s + 4]  * __expf(Ac[s + 4]  * dt) + u * b1[s];
        h[s + 8]  = h[s + 8]  * __expf(Ac[s + 8]  * dt) + u * b2[s];
        h[s + 12] = h[s + 12] * __expf(Ac[s + 12] * dt) + u * b3[s];
      }
    }
  }

  __shared__ float sdt_s[SCAN_CK][16];
  __shared__ float hc_s[SCAN_CK][16][17];    // hend in, hstart out (in-place)
  sdt_s[ck][dl] = sdt;
  #pragma unroll
  for (int s = 0; s < 16; ++s) hc_s[ck][dl][s] = h[s];
  __syncthreads();
  if (tid < 256) {
    const int s = tid >> 4;
    const float Acs = -__expf(lde(A_log, (size_t)di * 16 + s, f32));
    float hs = 0.f;
    #pragma unroll 4
    for (int c = 0; c < SCAN_CK; ++c) {
      const float hend = hc_s[c][dl][s];
      hc_s[c][dl][s] = hs;                   // hstart for chunk c
      hs = __expf(Acs * sdt_s[c][dl]) * hs + hend;
    }
  }
  __syncthreads();
  #pragma unroll
  for (int s = 0; s < 16; ++s) h[s] = hc_s[ck][dl][s];

  // pass 2: rescan with true h_start, emit y (coalesced across dl)
  if (pat) {
    #pragma unroll 2
    for (int t = 0; t < SCAN_ST; ++t) {
      const float dt = bf2f(dtp[(size_t)t * 2048]);
      const float xc = bf2f(xcp[(size_t)t * 2048]);
      const float4v b0 = *(const float4v*)&bmp[t * 16];
      const float4v b1 = *(const float4v*)&bmp[t * 16 + 4];
      const float4v b2 = *(const float4v*)&bmp[t * 16 + 8];
      const float4v b3 = *(const float4v*)&bmp[t * 16 + 12];
      const float4v c0 = *(const float4v*)&cmp[t * 16];
      const float4v c1 = *(const float4v*)&cmp[t * 16 + 4];
      const float4v c2 = *(const float4v*)&cmp[t * 16 + 8];
      const float4v c3 = *(const float4v*)&cmp[t * 16 + 12];
      const float u = xc * dt;
      float es[16];
      POWCHAIN(es, exp2f(al * dt));
      float p0 = 0.f, p1 = 0.f, p2 = 0.f, p3 = 0.f;
      #pragma unroll
      for (int s = 0; s < 4; ++s) {
        h[s]      = h[s]      * es[s]      + u * b0[s];
        h[s + 4]  = h[s + 4]  * es[s + 4]  + u * b1[s];
        h[s + 8]  = h[s + 8]  * es[s + 8]  + u * b2[s];
        h[s + 12] = h[s + 12] * es[s + 12] + u * b3[s];
        p0 += h[s] * c0[s];
        p1 += h[s + 4] * c1[s];
        p2 += h[s + 8] * c2[s];
        p3 += h[s + 12] * c3[s];
      }
      const float p = (p0 + p1) + (p2 + p3);
      const float z = bf2f(zp[(size_t)t * 4096]);
      const float sz = z * __builtin_amdgcn_rcpf(1.f + __expf(-z));
      yp[(size_t)t * 4096] = f2bf((p + xc * Dval) * sz);
    }
  } else {
    #pragma unroll 2
    for (int t = 0; t < SCAN_ST; ++t) {
      const float dt = bf2f(dtp[(size_t)t * 2048]);
      const float xc = bf2f(xcp[(size_t)t * 2048]);
      const float4v b0 = *(const float4v*)&bmp[t * 16];
      const float4v b1 = *(const float4v*)&bmp[t * 16 + 4];
      const float4v b2 = *(const float4v*)&bmp[t * 16 + 8];
      const float4v b3 = *(const float4v*)&bmp[t * 16 + 12];
      const float4v c0 = *(const float4v*)&cmp[t * 16];
      const float4v c1 = *(const float4v*)&cmp[t * 16 + 4];
      const float4v c2 = *(const float4v*)&cmp[t * 16 + 8];
      const float4v c3 = *(const float4v*)&cmp[t * 16 + 12];
      const float u = xc * dt;
      float p0 = 0.f, p1 = 0.f, p2 = 0.f, p3 = 0.f;
      #pragma unroll
      for (int s = 0; s < 4; ++s) {
        h[s]      = h[s]      * __expf(Ac[s]      * dt) + u * b0[s];
        h[s + 4]  = h[s + 4]  * __expf(Ac[s + 4]  * dt) + u * b1[s];
        h[s + 8]  = h[s + 8]  * __expf(Ac[s + 8]  * dt) + u * b2[s];
        h[s + 12] = h[s + 12] * __expf(Ac[s + 12] * dt) + u * b3[s];
        p0 += h[s] * c0[s];
        p1 += h[s + 4] * c1[s];
        p2 += h[s + 8] * c2[s];
        p3 += h[s + 12] * c3[s];
      }
      const float p = (p0 + p1) + (p2 + p3);
      const float z = bf2f(zp[(size_t)t * 4096]);
      const float sz = z * __builtin_amdgcn_rcpf(1.f + __expf(-z));
      yp[(size_t)t * 4096] = f2bf((p + xc * Dval) * sz);
    }
  }
#undef POWCHAIN
}

// -------- launch ----------
extern "C" void kernel_launch(void* const* d_in, const int* in_sizes, int n_in,
                              void* d_out, int out_size, void* d_ws, size_t ws_size,
                              hipStream_t stream) {
  const void* x      = d_in[0];
  const void* norm_w = d_in[1];
  const void* norm_b = d_in[2];
  const void* W_in   = d_in[3];
  const void* conv_w = d_in[4];
  const void* conv_b = d_in[5];
  const void* W_dt   = d_in[6];
  const void* b_dt   = d_in[7];
  const void* W_B    = d_in[8];
  const void* W_C    = d_in[9];
  const void* Dv     = d_in[10];
  const void* A_log  = d_in[11];
  const void* W_out  = d_in[12];

  char* ws = (char*)d_ws;
  const size_t MB = (size_t)1 << 20;
  short* wcvt = (short*)(ws);                 //  0-20.5 MB: W_in | [W_dt;W_B;W_C;pad] | W_out
  short* wbuf = wcvt;
  short* wcat = wcvt + WIN_N;                 // 2176 x 2048 bf16
  short* wout = wcvt + WIN_N + WCAT_N;
  int*   flag = (int*)(ws + 21 * MB - 256);
  short* xzb  = (short*)(ws + 21 * MB);       // 21-53 MB [4096 x 4096] (z kept; y overwrites x_part)
  short* xcv  = (short*)(ws + 53 * MB);       // 53-69 MB xc row-major
  short* xn   = (short*)(ws + 69 * MB);       //  8 MB (aliased with dtb)
  short* dtb  = (short*)(ws + 69 * MB);       // 69-85 MB dt row-major [(b,t)][di]
  float* Bm   = (float*)(ws + 85 * MB);       // 256 KB [(b,t)][s]
  float* Cm   = Bm + (size_t)NROWS * 16;      // 256 KB

  probe_kernel<<<1, 64, 0, stream>>>((const unsigned int*)x, flag);
  cvt_kernel<<<5248, 256, 0, stream>>>(W_in, W_dt, W_B, W_C, W_out, wcvt, flag);
  ln_kernel<<<NROWS, 256, 0, stream>>>(x, norm_w, norm_b, xn, flag);
  // gemm0: BM=256/BN=128, grid (32,16), 512 blocks (R4/R5 proven config)
  gemm_bt<0, 256><<<dim3(32, 16), 512, 0, stream>>>(xn, 1024, wbuf, xzb, 4096, 1024, nullptr, flag);
  conv_silu<<<NROWS / CONV_RPB, 256, 0, stream>>>(xzb, conv_w, conv_b, xcv, flag);
  // gemm1: R5 measured-best config — quad-buffer, grid (16,32)=512 blocks, N=2048
  gemm_bt<1, 128><<<dim3(16, 32), 256, 0, stream>>>(xcv, 2048, wcat, dtb, 2048, 2048, b_dt, flag);
  // Bm/Cm separate (fusion into gemm1 measured -49%: 544-block tail round, R8)
  bc_kernel<<<256, 256, 0, stream>>>(xcv, wcat + (size_t)2048 * 2048, Bm, Cm);
  scan_kernel<<<256, 1024, 0, stream>>>(dtb, xcv, Bm, Cm, xzb, A_log, Dv, flag);
  // gemm2: quad-buffer config, grid (8,32)=256 blocks
  gemm_bt<2, 128><<<dim3(8, 32), 256, 0, stream>>>(xzb, 4096, wout, d_out, 1024, 2048, x, flag);
}